// Round 1
// baseline (412.196 us; speedup 1.0000x reference)
//
#include <hip/hip_runtime.h>
#include <hip/hip_bf16.h>

// Gate kernel: logits = x[16384,4096] @ W[4096,64]; y = softmax(logits) * top2mask.
// Strategy: bf16 hi/lo split (x = xh + xl, W = wh + wl), 4 MFMA products
// (hh, lh, hl, ll) accumulated in fp32 -> ~fp32-accurate logits, HBM-bound.
// K1: convert W -> frag-tiled bf16 hi/lo in d_ws (1 MB).
// K2: split-K GEMM (512 WGs = 2/CU), atomicAdd partials into logits (d_out).
// K3: per-token softmax + top-2 mask (wave-wide, lane = expert).

typedef float f32x4 __attribute__((ext_vector_type(4)));
typedef __bf16 bf16x8 __attribute__((ext_vector_type(8)));

#define MFMA16(a, b, c) __builtin_amdgcn_mfma_f32_16x16x32_bf16((a), (b), (c), 0, 0, 0)

// ---------------- K1: W pre-pass -----------------------------------------
// Output layout (bf16 elements) per k-chunk kc (32 k's):
//   chunk base = kc*4096 elems (8192 B)
//   hi: base + nt*512 + (n&15)*32 + kk        (nt = n>>4, kk = k within chunk)
//   lo: base + 2048 + same
// This is exactly the 16x16x32 B-fragment tile order: lane l reads bytes
// (l&15)*64 + (l>>4)*16 within a 1 KB tile.
__global__ __launch_bounds__(256) void k_prep_w(const float* __restrict__ W,
                                                __bf16* __restrict__ wsW) {
  const int kc = blockIdx.x;      // 0..127
  const int t = threadIdx.x;
  const int kk0 = t >> 4;         // 0..15
  const int n0 = (t & 15) << 2;   // 0..60
  for (int i = 0; i < 2; ++i) {
    const int kk = kk0 + (i << 4);                  // 0..31
    const float4 w4 = *(const float4*)(W + (size_t)(kc * 32 + kk) * 64 + n0);
    const float f[4] = {w4.x, w4.y, w4.z, w4.w};
    for (int j = 0; j < 4; ++j) {
      const int n = n0 + j;
      const __bf16 h = (__bf16)f[j];
      const __bf16 l = (__bf16)(f[j] - (float)h);
      const int base = (kc << 12) + ((n >> 4) << 9) + ((n & 15) << 5) + kk;
      wsW[base] = h;
      wsW[base + 2048] = l;
    }
  }
}

// ---------------- K2: split-K GEMM ---------------------------------------
// x fp32 -> bf16 hi/lo split in-flight; LDS double buffered.
// A-frag layout (16x16x32): lane l -> A[m = l&15][k = (l>>4)*8 + j], j=0..7
// B-frag:                   lane l -> B[k = (l>>4)*8 + j][n = l&15]
// C/D:                      lane l, reg r -> C[m = (l>>4)*4 + r][n = l&15]
__device__ __forceinline__ void cvt_store(char* xb, int m, int lk, float4 v) {
  // xb tile layout: [mt = m>>4][m&15][k] bf16, 1024 B per 16x32 tile; lo at +4096.
  const int off = ((m >> 4) << 10) | ((m & 15) << 6) | ((lk >> 3) << 4) | ((lk & 7) << 1);
  const float f0 = v.x, f1 = v.y, f2 = v.z, f3 = v.w;
  const __bf16 h0 = (__bf16)f0, h1 = (__bf16)f1, h2 = (__bf16)f2, h3 = (__bf16)f3;
  const __bf16 l0 = (__bf16)(f0 - (float)h0), l1 = (__bf16)(f1 - (float)h1);
  const __bf16 l2 = (__bf16)(f2 - (float)h2), l3 = (__bf16)(f3 - (float)h3);
  uint2 uh, ul;
  uh.x = (unsigned)__builtin_bit_cast(unsigned short, h0) |
         ((unsigned)__builtin_bit_cast(unsigned short, h1) << 16);
  uh.y = (unsigned)__builtin_bit_cast(unsigned short, h2) |
         ((unsigned)__builtin_bit_cast(unsigned short, h3) << 16);
  ul.x = (unsigned)__builtin_bit_cast(unsigned short, l0) |
         ((unsigned)__builtin_bit_cast(unsigned short, l1) << 16);
  ul.y = (unsigned)__builtin_bit_cast(unsigned short, l2) |
         ((unsigned)__builtin_bit_cast(unsigned short, l3) << 16);
  *(uint2*)(xb + off) = uh;
  *(uint2*)(xb + 4096 + off) = ul;
}

__global__ __launch_bounds__(256, 2) void k_gemm(const float* __restrict__ x,
                                                 const __bf16* __restrict__ wsW,
                                                 float* __restrict__ logits) {
  // LDS: x: 2 bufs x 8 KB ([hi 4K][lo 4K]); W: 2 bufs x 8 KB. Total 32 KB.
  __shared__ __align__(16) char smem[32768];
  char* xs = smem;
  char* wsb = smem + 16384;

  const int t = threadIdx.x;
  const int blk = blockIdx.x;
  const int mb = blk >> 1;        // 0..255 -> 64-token tile
  const int ks = blk & 1;         // K split half
  const size_t gm0 = (size_t)mb * 64;
  const int kc0 = ks << 6;        // chunk index base (64 chunks of 32 k each)

  // x staging: thread loads rows lm and lm+32, cols lk..lk+3 of the 64x32 chunk
  const int lm = t >> 3;          // 0..31
  const int lk = (t & 7) << 2;    // 0,4,...,28
  const float* xg = x + (gm0 + lm) * 4096 + (size_t)kc0 * 32 + lk;
  // W staging: thread copies bytes [t*16] and [4096 + t*16] of the 8 KB chunk
  const char* wg = (const char*)wsW + (size_t)kc0 * 8192;
  const int wOffA = t << 4;
  const int wOffB = 4096 + (t << 4);

  const int w = t >> 6, l = t & 63;
  const int mtb = (w & 1) << 1;   // wave's m-tile pair
  const int ntb = (w >> 1) << 1;  // wave's n-tile pair
  const int tileoff = ((l & 15) << 6) + ((l >> 4) << 4);

  f32x4 acc00 = {0.f, 0.f, 0.f, 0.f};
  f32x4 acc01 = {0.f, 0.f, 0.f, 0.f};
  f32x4 acc10 = {0.f, 0.f, 0.f, 0.f};
  f32x4 acc11 = {0.f, 0.f, 0.f, 0.f};

  // prologue: chunk 0 into registers
  float4 xr0 = *(const float4*)(xg);
  float4 xr1 = *(const float4*)(xg + 32 * 4096);
  uint4 wr0 = *(const uint4*)(wg + wOffA);
  uint4 wr1 = *(const uint4*)(wg + wOffB);

  for (int c = 0; c < 64; ++c) {
    char* xb = xs + ((c & 1) << 13);
    char* wb = wsb + ((c & 1) << 13);
    cvt_store(xb, lm, lk, xr0);
    cvt_store(xb, lm + 32, lk, xr1);
    *(uint4*)(wb + wOffA) = wr0;
    *(uint4*)(wb + wOffB) = wr1;
    __syncthreads();
    if (c < 63) {  // prefetch next chunk into registers (in flight during compute)
      xr0 = *(const float4*)(xg + (c + 1) * 32);
      xr1 = *(const float4*)(xg + (c + 1) * 32 + 32 * 4096);
      wr0 = *(const uint4*)(wg + (c + 1) * 8192 + wOffA);
      wr1 = *(const uint4*)(wg + (c + 1) * 8192 + wOffB);
    }
    const bf16x8 ah0 = *(const bf16x8*)(xb + (mtb + 0) * 1024 + tileoff);
    const bf16x8 ah1 = *(const bf16x8*)(xb + (mtb + 1) * 1024 + tileoff);
    const bf16x8 al0 = *(const bf16x8*)(xb + 4096 + (mtb + 0) * 1024 + tileoff);
    const bf16x8 al1 = *(const bf16x8*)(xb + 4096 + (mtb + 1) * 1024 + tileoff);
    const bf16x8 bh0 = *(const bf16x8*)(wb + (ntb + 0) * 1024 + tileoff);
    const bf16x8 bh1 = *(const bf16x8*)(wb + (ntb + 1) * 1024 + tileoff);
    const bf16x8 bl0 = *(const bf16x8*)(wb + 4096 + (ntb + 0) * 1024 + tileoff);
    const bf16x8 bl1 = *(const bf16x8*)(wb + 4096 + (ntb + 1) * 1024 + tileoff);
    // full product: (ah+al)*(bh+bl)
    acc00 = MFMA16(ah0, bh0, acc00); acc00 = MFMA16(al0, bh0, acc00);
    acc00 = MFMA16(ah0, bl0, acc00); acc00 = MFMA16(al0, bl0, acc00);
    acc01 = MFMA16(ah0, bh1, acc01); acc01 = MFMA16(al0, bh1, acc01);
    acc01 = MFMA16(ah0, bl1, acc01); acc01 = MFMA16(al0, bl1, acc01);
    acc10 = MFMA16(ah1, bh0, acc10); acc10 = MFMA16(al1, bh0, acc10);
    acc10 = MFMA16(ah1, bl0, acc10); acc10 = MFMA16(al1, bl0, acc10);
    acc11 = MFMA16(ah1, bh1, acc11); acc11 = MFMA16(al1, bh1, acc11);
    acc11 = MFMA16(ah1, bl1, acc11); acc11 = MFMA16(al1, bl1, acc11);
    __syncthreads();
  }

  // epilogue: atomic accumulate partials (2 commutative adds/elem -> deterministic)
  float* lbase = logits + gm0 * 64;
  const int q = (l >> 4) << 2, ln = l & 15;
  for (int r = 0; r < 4; ++r) {
    const int m0 = (mtb + 0) * 16 + q + r;
    const int m1 = (mtb + 1) * 16 + q + r;
    atomicAdd(lbase + (size_t)m0 * 64 + (ntb + 0) * 16 + ln, acc00[r]);
    atomicAdd(lbase + (size_t)m0 * 64 + (ntb + 1) * 16 + ln, acc01[r]);
    atomicAdd(lbase + (size_t)m1 * 64 + (ntb + 0) * 16 + ln, acc10[r]);
    atomicAdd(lbase + (size_t)m1 * 64 + (ntb + 1) * 16 + ln, acc11[r]);
  }
}

// ---------------- K3: softmax + top-2 mask -------------------------------
__global__ __launch_bounds__(256) void k_softmax_top2(const float* __restrict__ logits,
                                                      float* __restrict__ y) {
  const int t = threadIdx.x, w = t >> 6, l = t & 63;
  const size_t tok0 = (size_t)blockIdx.x * 64 + w * 16;
  for (int i = 0; i < 16; ++i) {
    const size_t tok = tok0 + i;
    const float v = logits[tok * 64 + l];
    // argmax (lowest index on ties, matching jax.lax.top_k)
    float bv = v; int bi = l;
    for (int off = 32; off > 0; off >>= 1) {
      const float ov = __shfl_xor(bv, off);
      const int oi = __shfl_xor(bi, off);
      if (ov > bv || (ov == bv && oi < bi)) { bv = ov; bi = oi; }
    }
    const int i1 = bi;
    const float m1 = bv;
    float cv = (l == i1) ? -3.402823466e38f : v;
    int ci = l;
    for (int off = 32; off > 0; off >>= 1) {
      const float ov = __shfl_xor(cv, off);
      const int oi = __shfl_xor(ci, off);
      if (ov > cv || (ov == cv && oi < ci)) { cv = ov; ci = oi; }
    }
    const int i2 = ci;
    const float e = __expf(v - m1);
    float s = e;
    for (int off = 32; off > 0; off >>= 1) s += __shfl_xor(s, off);
    y[tok * 64 + l] = ((l == i1) || (l == i2)) ? (e / s) : 0.0f;
  }
}

// ---------------- launcher ------------------------------------------------
extern "C" void kernel_launch(void* const* d_in, const int* in_sizes, int n_in,
                              void* d_out, int out_size, void* d_ws, size_t ws_size,
                              hipStream_t stream) {
  (void)in_sizes; (void)n_in; (void)out_size; (void)ws_size;
  const float* x = (const float*)d_in[0];
  const float* W = (const float*)d_in[1];
  float* out = (float*)d_out;
  float* yout = out;                    // [16384,64]
  float* logits = out + 1048576;        // [16384,64]
  __bf16* wsW = (__bf16*)d_ws;          // 1 MB frag-tiled bf16 hi/lo W

  k_prep_w<<<128, 256, 0, stream>>>(W, wsW);
  hipMemsetAsync(logits, 0, 4194304, stream);
  k_gemm<<<512, 256, 0, stream>>>(x, wsW, logits);
  k_softmax_top2<<<256, 256, 0, stream>>>(logits, yout);
}

// Round 2
// 409.855 us; speedup vs baseline: 1.0057x; 1.0057x over previous
//
#include <hip/hip_runtime.h>
#include <hip/hip_bf16.h>

// Gate: logits = x[16384,4096] @ W[4096,64]; y = softmax(logits) * top2mask.
// bf16 hi/lo split GEMM (hh + lh + hl products; ll dropped, ~2e-5 error),
// fp32 MFMA accumulate. Barrier-free K-loop: A-fragments loaded per-lane
// straight from global x (32 B contiguous/lane), B-fragments per-lane from
// pre-tiled L2-resident wsW. Register double-stage prefetch (distance 2).
// Single fused kernel: GEMM -> LDS logits tile -> softmax+top2 -> y, logits.

typedef float f32x4 __attribute__((ext_vector_type(4)));
typedef __bf16 bf16x8 __attribute__((ext_vector_type(8)));

#define MFMA16(a, b, c) __builtin_amdgcn_mfma_f32_16x16x32_bf16((a), (b), (c), 0, 0, 0)

// ---------------- K1: W pre-pass (fragment-tiled bf16 hi/lo, 1 MB) -------
// Per k-chunk kc (32 k's), chunk base = kc*4096 bf16 elems:
//   hi: base + nt*512 + (n&15)*32 + kk ; lo: +2048
// Lane l of a 16x16x32 B-frag reads elems (l&15)*32 + (l>>4)*8 .. +7 (16 B).
__global__ __launch_bounds__(256) void k_prep_w(const float* __restrict__ W,
                                                __bf16* __restrict__ wsW) {
  const int kc = blockIdx.x;      // 0..127
  const int t = threadIdx.x;
  const int kk0 = t >> 4;         // 0..15
  const int n0 = (t & 15) << 2;   // 0..60
  for (int i = 0; i < 2; ++i) {
    const int kk = kk0 + (i << 4);
    const float4 w4 = *(const float4*)(W + (size_t)(kc * 32 + kk) * 64 + n0);
    const float f[4] = {w4.x, w4.y, w4.z, w4.w};
    for (int j = 0; j < 4; ++j) {
      const int n = n0 + j;
      const __bf16 h = (__bf16)f[j];
      const __bf16 l = (__bf16)(f[j] - (float)h);
      const int base = (kc << 12) + ((n >> 4) << 9) + ((n & 15) << 5) + kk;
      wsW[base] = h;
      wsW[base + 2048] = l;
    }
  }
}

// ---------------- fused gate kernel --------------------------------------
// Grid 512 x 256. WG = 32 tokens; wave w: m-tile mt=w&1 (rows mt*16..+15),
// n-half nh=w>>1 (experts nh*32..+31 = 2 n-tiles).
// A-frag (16x16x32): lane l -> A[m=l&15][k=(l>>4)*8+j]
// C/D: lane l, reg r -> C[row=(l>>4)*4+r][col=l&15]
__global__ __launch_bounds__(256, 2) void k_gate(const float* __restrict__ x,
                                                 const __bf16* __restrict__ wsW,
                                                 float* __restrict__ y,
                                                 float* __restrict__ logits) {
  const int t = threadIdx.x;
  const int w = t >> 6, l = t & 63;
  const int tb = blockIdx.x * 32;
  const int mt = w & 1, nh = w >> 1;
  const int q = l >> 4, ln = l & 15;

  const float* xp = x + (size_t)(tb + mt * 16 + ln) * 4096 + q * 8;
  const __bf16* wp = wsW + (nh * 2) * 512 + ln * 32 + q * 8;

  f32x4 acc0 = {0.f, 0.f, 0.f, 0.f};
  f32x4 acc1 = {0.f, 0.f, 0.f, 0.f};

  float4 xa0, xb0, xa1, xb1;
  bf16x8 h0_0, l0_0, h1_0, l1_0;
  bf16x8 h0_1, l0_1, h1_1, l1_1;

#define LOAD_STAGE(S, c) do {                                          \
    xa##S = *(const float4*)(xp + (size_t)(c) * 32);                   \
    xb##S = *(const float4*)(xp + (size_t)(c) * 32 + 4);               \
    h0_##S = *(const bf16x8*)(wp + (size_t)(c) * 4096);                \
    l0_##S = *(const bf16x8*)(wp + (size_t)(c) * 4096 + 2048);         \
    h1_##S = *(const bf16x8*)(wp + (size_t)(c) * 4096 + 512);          \
    l1_##S = *(const bf16x8*)(wp + (size_t)(c) * 4096 + 2560);         \
  } while (0)

#define COMPUTE(S) do {                                                \
    bf16x8 ah, al;                                                     \
    const float f[8] = {xa##S.x, xa##S.y, xa##S.z, xa##S.w,            \
                        xb##S.x, xb##S.y, xb##S.z, xb##S.w};           \
    _Pragma("unroll")                                                  \
    for (int i = 0; i < 8; ++i) {                                      \
      const __bf16 hh = (__bf16)f[i];                                  \
      ah[i] = hh;                                                      \
      al[i] = (__bf16)(f[i] - (float)hh);                              \
    }                                                                  \
    acc0 = MFMA16(ah, h0_##S, acc0);                                   \
    acc0 = MFMA16(al, h0_##S, acc0);                                   \
    acc0 = MFMA16(ah, l0_##S, acc0);                                   \
    acc1 = MFMA16(ah, h1_##S, acc1);                                   \
    acc1 = MFMA16(al, h1_##S, acc1);                                   \
    acc1 = MFMA16(ah, l1_##S, acc1);                                   \
  } while (0)

  LOAD_STAGE(0, 0);
  LOAD_STAGE(1, 1);
  for (int c = 0; c < 128; c += 2) {
    COMPUTE(0);
    if (c + 2 < 128) LOAD_STAGE(0, c + 2);
    COMPUTE(1);
    if (c + 3 < 128) LOAD_STAGE(1, c + 3);
  }
#undef LOAD_STAGE
#undef COMPUTE

  // epilogue: stash logits tile to LDS (stride 65 -> conflict-free) + global
  __shared__ float lt[32 * 65];
  const int col = nh * 32 + ln;
#pragma unroll
  for (int r = 0; r < 4; ++r) {
    const int row = mt * 16 + q * 4 + r;
    lt[row * 65 + col] = acc0[r];
    lt[row * 65 + col + 16] = acc1[r];
    logits[(size_t)(tb + row) * 64 + col] = acc0[r];
    logits[(size_t)(tb + row) * 64 + col + 16] = acc1[r];
  }
  __syncthreads();

  // softmax + top-2 (lane = expert; ties -> lowest index, matching top_k)
#pragma unroll
  for (int i = 0; i < 8; ++i) {
    const int tok = w * 8 + i;
    const float v = lt[tok * 65 + l];
    float bv = v; int bi = l;
    for (int off = 32; off; off >>= 1) {
      const float ov = __shfl_xor(bv, off);
      const int oi = __shfl_xor(bi, off);
      if (ov > bv || (ov == bv && oi < bi)) { bv = ov; bi = oi; }
    }
    const int i1 = bi;
    const float m1 = bv;
    float cv = (l == i1) ? -3.402823466e38f : v;
    int ci = l;
    for (int off = 32; off; off >>= 1) {
      const float ov = __shfl_xor(cv, off);
      const int oi = __shfl_xor(ci, off);
      if (ov > cv || (ov == cv && oi < ci)) { cv = ov; ci = oi; }
    }
    const float e = __expf(v - m1);
    float s = e;
    for (int off = 32; off; off >>= 1) s += __shfl_xor(s, off);
    y[(size_t)(tb + tok) * 64 + l] = (l == i1 || l == ci) ? (e / s) : 0.0f;
  }
}

// ---------------- launcher ------------------------------------------------
extern "C" void kernel_launch(void* const* d_in, const int* in_sizes, int n_in,
                              void* d_out, int out_size, void* d_ws, size_t ws_size,
                              hipStream_t stream) {
  (void)in_sizes; (void)n_in; (void)out_size; (void)ws_size;
  const float* x = (const float*)d_in[0];
  const float* W = (const float*)d_in[1];
  float* out = (float*)d_out;
  float* yout = out;                 // [16384,64]
  float* logits = out + 1048576;     // [16384,64]
  __bf16* wsW = (__bf16*)d_ws;       // 1 MB frag-tiled bf16 hi/lo W

  k_prep_w<<<128, 256, 0, stream>>>(W, wsW);
  k_gate<<<512, 256, 0, stream>>>(x, wsW, yout, logits);
}

// Round 3
// 404.501 us; speedup vs baseline: 1.0190x; 1.0132x over previous
//
#include <hip/hip_runtime.h>
#include <hip/hip_bf16.h>

// Gate: logits = x[16384,4096] @ W[4096,64]; y = softmax(logits) * top2mask.
// Full 4-product bf16 hi/lo split GEMM (hh+lh+hl+ll), fp32 MFMA accumulate.
// Barrier-free K-loop, 4-stage register prefetch (24 KB in flight/wave) to
// cover ~900-cyc HBM latency. W pre-tiled in d_ws so all fragment offsets
// fit 13-bit load immediates; pointers advanced once per 4-chunk iteration.

typedef float f32x4 __attribute__((ext_vector_type(4)));
typedef __bf16 bf16x8 __attribute__((ext_vector_type(8)));

#define MFMA16(a, b, c) __builtin_amdgcn_mfma_f32_16x16x32_bf16((a), (b), (c), 0, 0, 0)

// ---------------- K1: W pre-pass (fragment-tiled bf16 hi/lo, 1 MB) -------
// Per k-chunk kc (32 k's), chunk base = kc*4096 elems. Tile nt (16 experts):
//   tile base = chunk + nt*1024; hi frag at +0 (elem (n&15)*32 + kk),
//   lo frag at +512. Lane l of a B-frag reads elems (l&15)*32+(l>>4)*8..+7.
__global__ __launch_bounds__(256) void k_prep_w(const float* __restrict__ W,
                                                __bf16* __restrict__ wsW) {
  const int kc = blockIdx.x;      // 0..127
  const int t = threadIdx.x;
  const int kk0 = t >> 4;         // 0..15
  const int n0 = (t & 15) << 2;   // 0..60
  for (int i = 0; i < 2; ++i) {
    const int kk = kk0 + (i << 4);
    const float4 w4 = *(const float4*)(W + (size_t)(kc * 32 + kk) * 64 + n0);
    const float f[4] = {w4.x, w4.y, w4.z, w4.w};
    for (int j = 0; j < 4; ++j) {
      const int n = n0 + j;
      const __bf16 h = (__bf16)f[j];
      const __bf16 l = (__bf16)(f[j] - (float)h);
      const int base = (kc << 12) + ((n >> 4) << 10) + ((n & 15) << 5) + kk;
      wsW[base] = h;
      wsW[base + 512] = l;
    }
  }
}

// exact truncation split: hi = top 16 bits of f (as bf16), lo = f - hi (exact
// in fp32), lo then RNE-rounded to bf16. Combined ~24 mantissa bits.
__device__ __forceinline__ void split8(const float4 a, const float4 b,
                                       bf16x8& hi, bf16x8& lo) {
  const float f[8] = {a.x, a.y, a.z, a.w, b.x, b.y, b.z, b.w};
#pragma unroll
  for (int i = 0; i < 8; ++i) {
    const unsigned u = __builtin_bit_cast(unsigned, f[i]);
    hi[i] = __builtin_bit_cast(__bf16, (unsigned short)(u >> 16));
    lo[i] = (__bf16)(f[i] - __builtin_bit_cast(float, u & 0xFFFF0000u));
  }
}

// ---------------- fused gate kernel --------------------------------------
// Grid 512 x 256. WG = 32 tokens; wave w: m-tile mt=w&1 (rows mt*16..+15),
// n-half nh=w>>1 (experts nh*32..+31 = 2 tiles).
// A-frag (16x16x32): lane l -> A[m=l&15][k=(l>>4)*8+j]
// C/D: lane l, reg r -> C[row=(l>>4)*4+r][col=l&15]
__global__ __launch_bounds__(256, 2) void k_gate(const float* __restrict__ x,
                                                 const __bf16* __restrict__ wsW,
                                                 float* __restrict__ y,
                                                 float* __restrict__ logits) {
  const int t = threadIdx.x;
  const int w = t >> 6, l = t & 63;
  const int tb = blockIdx.x * 32;
  const int mt = w & 1, nh = w >> 1;
  const int q = l >> 4, ln = l & 15;

  const float* xp = x + (size_t)(tb + mt * 16 + ln) * 4096 + q * 8;
  // per-stage W pointers; all frag offsets within a stage fit load immediates
  const __bf16* wq = wsW + nh * 2048 + ln * 32 + q * 8;
  const __bf16* wp0 = wq;
  const __bf16* wp1 = wq + 4096;
  const __bf16* wp2 = wq + 8192;
  const __bf16* wp3 = wq + 12288;

  f32x4 acc0 = {0.f, 0.f, 0.f, 0.f};
  f32x4 acc1 = {0.f, 0.f, 0.f, 0.f};

  float4 xa[4], xb[4];
  bf16x8 wh0[4], wl0[4], wh1[4], wl1[4];

#define LOADX(S) do {                                                   \
    xa[S] = *(const float4*)(xp + (S) * 32);                            \
    xb[S] = *(const float4*)(xp + (S) * 32 + 4);                        \
  } while (0)
#define LOADW(S, P) do {                                                \
    wh0[S] = *(const bf16x8*)((P));                                     \
    wl0[S] = *(const bf16x8*)((P) + 512);                               \
    wh1[S] = *(const bf16x8*)((P) + 1024);                              \
    wl1[S] = *(const bf16x8*)((P) + 1536);                              \
  } while (0)
#define COMP(S) do {                                                    \
    bf16x8 ah, al;                                                      \
    split8(xa[S], xb[S], ah, al);                                       \
    acc0 = MFMA16(ah, wh0[S], acc0);                                    \
    acc0 = MFMA16(al, wh0[S], acc0);                                    \
    acc0 = MFMA16(ah, wl0[S], acc0);                                    \
    acc0 = MFMA16(al, wl0[S], acc0);                                    \
    acc1 = MFMA16(ah, wh1[S], acc1);                                    \
    acc1 = MFMA16(al, wh1[S], acc1);                                    \
    acc1 = MFMA16(ah, wl1[S], acc1);                                    \
    acc1 = MFMA16(al, wl1[S], acc1);                                    \
  } while (0)

  // prologue: stages 0..3 = chunks 0..3
  LOADX(0); LOADX(1); LOADX(2); LOADX(3);
  LOADW(0, wp0); LOADW(1, wp1); LOADW(2, wp2); LOADW(3, wp3);
  xp += 128; wp0 += 16384; wp1 += 16384; wp2 += 16384; wp3 += 16384;

  // 31 steady-state iterations (compute chunks c..c+3, load c+4..c+7)
  for (int it = 0; it < 31; ++it) {
    COMP(0); LOADX(0); LOADW(0, wp0);
    COMP(1); LOADX(1); LOADW(1, wp1);
    COMP(2); LOADX(2); LOADW(2, wp2);
    COMP(3); LOADX(3); LOADW(3, wp3);
    xp += 128; wp0 += 16384; wp1 += 16384; wp2 += 16384; wp3 += 16384;
  }
  // tail: chunks 124..127
  COMP(0); COMP(1); COMP(2); COMP(3);
#undef LOADX
#undef LOADW
#undef COMP

  // epilogue: logits tile to LDS (stride 65, conflict-free) + global
  __shared__ float lt[32 * 65];
  const int col = nh * 32 + ln;
#pragma unroll
  for (int r = 0; r < 4; ++r) {
    const int row = mt * 16 + q * 4 + r;
    lt[row * 65 + col] = acc0[r];
    lt[row * 65 + col + 16] = acc1[r];
    logits[(size_t)(tb + row) * 64 + col] = acc0[r];
    logits[(size_t)(tb + row) * 64 + col + 16] = acc1[r];
  }
  __syncthreads();

  // softmax + top-2 (lane = expert; ties -> lowest index, matching top_k)
#pragma unroll
  for (int i = 0; i < 8; ++i) {
    const int tok = w * 8 + i;
    const float v = lt[tok * 65 + l];
    float bv = v; int bi = l;
    for (int off = 32; off; off >>= 1) {
      const float ov = __shfl_xor(bv, off);
      const int oi = __shfl_xor(bi, off);
      if (ov > bv || (ov == bv && oi < bi)) { bv = ov; bi = oi; }
    }
    const int i1 = bi;
    const float m1 = bv;
    float cv = (l == i1) ? -3.402823466e38f : v;
    int ci = l;
    for (int off = 32; off; off >>= 1) {
      const float ov = __shfl_xor(cv, off);
      const int oi = __shfl_xor(ci, off);
      if (ov > cv || (ov == cv && oi < ci)) { cv = ov; ci = oi; }
    }
    const float e = __expf(v - m1);
    float s = e;
    for (int off = 32; off; off >>= 1) s += __shfl_xor(s, off);
    y[(size_t)(tb + tok) * 64 + l] = (l == i1 || l == ci) ? (e / s) : 0.0f;
  }
}

// ---------------- launcher ------------------------------------------------
extern "C" void kernel_launch(void* const* d_in, const int* in_sizes, int n_in,
                              void* d_out, int out_size, void* d_ws, size_t ws_size,
                              hipStream_t stream) {
  (void)in_sizes; (void)n_in; (void)out_size; (void)ws_size;
  const float* x = (const float*)d_in[0];
  const float* W = (const float*)d_in[1];
  float* out = (float*)d_out;
  float* yout = out;                 // [16384,64]
  float* logits = out + 1048576;     // [16384,64]
  __bf16* wsW = (__bf16*)d_ws;       // 1 MB frag-tiled bf16 hi/lo W

  k_prep_w<<<128, 256, 0, stream>>>(W, wsW);
  k_gate<<<512, 256, 0, stream>>>(x, wsW, yout, logits);
}